// Round 16
// baseline (234.694 us; speedup 1.0000x reference)
//
#include <hip/hip_runtime.h>
#include <math.h>

// Problem constants (N = 1024)
#define M_ROWS  81920            // 1024*8*10 score rows
#define NCOLS   4096
#define KPAD    48               // 45 padded to 48 (3 k-tiles of 16 for 32x32x16)
#define NCHUNK  8
#define CHUNKC  (NCOLS / NCHUNK) // 512 cols per chunk
#define CROUNDS (CHUNKC / 32)    // 16 col-rounds of 32 cols
#define GHALVES 3072             // _Float16 per 32-col group: 6 bufs * 512
#define LO_SCALE 4096.0f         // 2^12: keeps f16 residuals out of subnormal range
#define INV_LO   (1.0f / 4096.0f)

typedef _Float16 f16x8  __attribute__((ext_vector_type(8)));
typedef float    f32x16 __attribute__((ext_vector_type(16)));

// ws layout (1.41 MB):
//   Bfrag: _Float16[128 groups][6 bufs][512]  fragment-major   0.75 MB
//   keys : u64[81920]  packed (mono-score<<32 | 4095-col)      0.66 MB
//
// MEASURED LADDER (r0-r15, score-kernel µs): r13=131 best structure
// (frag-major + ping-pong dbuf). Plateau diagnosis: occupancy is
// register-limited to 4 waves/SIMD (64 arch + ~64 acc VGPR; r14: arg2 3
// changed nothing); no pipe >52%; 8-way stream sharing neutral (r15).
// Remaining measured inefficiency: FILL IMBALANCE -- r13 runs 2.5 fills
// (2560 residency-units / 512 slots) and pays 3 block-generations.
// THIS KERNEL: NCHUNK=8, block = 8 waves = 2 chunks x 4 row-tiles,
// 2560 blocks = EXACTLY 5 fills at the measured 2-blocks/CU residency.
// Same per-round loop as r13/r15; cross-chunk fold via r12/r15-proven
// packed-u64 atomicMax (no LDS, no extra barrier).
//
// Launch-bounds law (measured r0,r2,r3,r8,r14): arch-VGPR cap = 256/arg2;
// arg2 also upper-bounds blocks/CU; actual residency = register-limited.
// (512,2): 128-VGPR cap; r13-profile kernel fits -> no spill.

// ---------------------------------------------------------------------------
// Build Bfrag: split H (45 x 4096, [d][n]) into hi/lo f16, emit in
// fragment-major order. Lane mapping within a buffer: lane = half*32 + c,
// holding col (g*32+c), k's [kt*16 + half*8, +8), pad k=45..47 zeroed.
// Also zeroes keys (stream-ordered before the score kernel's atomics);
// key 0 < any real packed key.
__global__ void build_B_kernel(const float* __restrict__ H,
                               _Float16* __restrict__ Bfrag,
                               unsigned long long* __restrict__ keys) {
    const int n = blockIdx.x * 256 + threadIdx.x;     // col [0,4096)
    _Float16 hi[KPAD], lo[KPAD];
    #pragma unroll
    for (int k = 0; k < 45; ++k) {
        const float h = H[k * NCOLS + n];
        const _Float16 h1 = (_Float16)h;
        hi[k] = h1;
        lo[k] = (_Float16)((h - (float)h1) * LO_SCALE);
    }
    #pragma unroll
    for (int k = 45; k < KPAD; ++k) { hi[k] = (_Float16)0.f; lo[k] = (_Float16)0.f; }

    const int g = n >> 5;
    const int c = n & 31;
    _Float16* gbase = Bfrag + (size_t)g * GHALVES;
    #pragma unroll
    for (int f = 0; f < 6; ++f) {
        const int kt = (f < 3) ? f : f - 3;
        const _Float16* src = ((f < 3) ? hi : lo) + kt * 16;
        #pragma unroll
        for (int h = 0; h < 2; ++h) {
            // lane = h*32 + c  ->  halves offset lane*8
            *(f16x8*)(gbase + f * 512 + (h * 32 + c) * 8) =
                *(const f16x8*)(src + h * 8);
        }
    }
    // zero keys: 81920 = 4096 threads * 20
    #pragma unroll
    for (int i = 0; i < 20; ++i) keys[(size_t)n * 20 + i] = 0ull;
}

// ---------------------------------------------------------------------------
// MFMA GEMM + fused argmax. Block = 512 threads = 8 waves = 2 chunks x
// 4 row-tiles: wave w -> chunk chunkpair*2 + (w&1), rows rowblk + (w>>1)*32.
// 2560 blocks = 640 row-blocks (128 rows) x 4 chunk-pairs = 5 exact fills.
// Per-wave loop identical to r13/r15 (ping-pong dbuf, wrap &15).
// Cross-chunk fold: packed-u64 atomicMax (r12/r15-proven, first-index-exact).
// 32x32 layouts: A[m=lane&31][k=(lane>>5)*8+j]; B[k=(lane>>5)*8+j][n=lane&31];
// C/D: col=lane&31, row=(reg&3)+8*(reg>>2)+4*(lane>>5)   (m74/m101-verified).
__global__ __launch_bounds__(512, 2) void score_argmax_kernel(
        const float* __restrict__ x,   // (1024, 480)
        const float* __restrict__ S,   // (30, 2, 15)
        const float* __restrict__ T,   // (30, 15)
        const _Float16* __restrict__ Bfrag,
        unsigned long long* __restrict__ keys) {
    const int tid  = threadIdx.x;
    const int lane = tid & 63;
    const int l31  = lane & 31;
    const int half = lane >> 5;                       // 0 or 1
    const int wid  = tid >> 6;                        // wave id [0,8)
    const int cpair  = blockIdx.x / 640;              // chunk-pair [0,4)
    const int rowblk = (blockIdx.x - cpair * 640) * 128;
    const int chunk  = cpair * 2 + (wid & 1);         // [0,8)
    const int rowbase = rowblk + (wid >> 1) * 32;     // wave's first row

    // ---- inline A: afr[kt][j] = y(rowbase + l31, kt*16 + half*8 + j)
    // y = sign(x4·S - T - 1e-4), exactly ±1/0 in f16; zero for k >= 45.
    f16x8 afr[3];
    {
        const int row  = rowbase + l31;
        const int pair = row / 10;
        const int c2   = row - pair * 10;
        const int a    = pair >> 3;
        const int b    = pair & 7;
        const float* xp = x + a * 480 + b * 60;
        #pragma unroll
        for (int kt = 0; kt < 3; ++kt) {
            #pragma unroll
            for (int j = 0; j < 8; ++j) {
                const int k    = kt * 16 + half * 8 + j;     // [0,48)
                const bool pad = (k >= 45);
                const int kcl  = pad ? 0 : k;                // clamp for safe addrs
                const int cc   = kcl / 15;                   // const-divisor magic
                const int kk   = kcl - cc * 15;
                const int c    = c2 * 3 + cc;
                const float x0 = xp[c * 2 + 0];
                const float x1 = xp[c * 2 + 1];
                float v = x0 * S[(c * 2 + 0) * 15 + kk] + x1 * S[(c * 2 + 1) * 15 + kk];
                v = v - T[c * 15 + kk] - 1e-4f;
                const float yv = (v > 0.f) ? 1.f : ((v < 0.f) ? -1.f : 0.f);
                afr[kt][j] = pad ? (_Float16)0.f : (_Float16)yv;
            }
        }
    }

    float best[16];
    int   bidx[16];
    #pragma unroll
    for (int e = 0; e < 16; ++e) { best[e] = -INFINITY; bidx[e] = 0; }

    const int colbase0 = chunk * CHUNKC;
    const int gbase0   = colbase0 >> 5;               // first group of chunk
    const _Float16* lanep = Bfrag + (size_t)lane * 8;

    // PREFETCH round rr (wrapped into [0,16) by caller): 6 x 1KB coalesced
#define PREFETCH(dst, rr) do {                                              \
        const _Float16* fp_ = lanep + (size_t)(gbase0 + (rr)) * GHALVES;    \
        _Pragma("unroll")                                                   \
        for (int f_ = 0; f_ < 6; ++f_)                                      \
            (dst)[f_] = *(const f16x8*)(fp_ + f_ * 512);                    \
    } while (0)

#define COMPUTE(buf, ct) do {                                               \
        f32x16 ch = {0.f};                                                  \
        f32x16 cl = {0.f};                                                  \
        ch = __builtin_amdgcn_mfma_f32_32x32x16_f16(afr[0], (buf)[0], ch, 0, 0, 0); \
        ch = __builtin_amdgcn_mfma_f32_32x32x16_f16(afr[1], (buf)[1], ch, 0, 0, 0); \
        ch = __builtin_amdgcn_mfma_f32_32x32x16_f16(afr[2], (buf)[2], ch, 0, 0, 0); \
        cl = __builtin_amdgcn_mfma_f32_32x32x16_f16(afr[0], (buf)[3], cl, 0, 0, 0); \
        cl = __builtin_amdgcn_mfma_f32_32x32x16_f16(afr[1], (buf)[4], cl, 0, 0, 0); \
        cl = __builtin_amdgcn_mfma_f32_32x32x16_f16(afr[2], (buf)[5], cl, 0, 0, 0); \
        const int mycol_ = colbase0 + (ct) * 32 + l31;                      \
        _Pragma("unroll")                                                   \
        for (int e_ = 0; e_ < 16; ++e_) {                                   \
            const float s_ = fmaf(cl[e_], INV_LO, ch[e_]);                  \
            if (s_ > best[e_]) bidx[e_] = mycol_;   /* cols ascend */       \
            best[e_] = fmaxf(best[e_], s_);                                 \
        }                                                                   \
    } while (0)

    // ping-pong x2 unroll: no per-round register copies; prefetch index
    // wraps &15 (stays inside the chunk: no overread, no ws slack needed).
    f16x8 cb[6], nb[6];
    PREFETCH(cb, 0);
    for (int it = 0; it < CROUNDS; it += 2) {
        PREFETCH(nb, it + 1);                 // it+1 <= 15: in range
        COMPUTE(cb, it);
        PREFETCH(cb, (it + 2) & 15);          // wrap: in range, values unused
        COMPUTE(nb, it + 1);
    }
#undef PREFETCH
#undef COMPUTE

    // Cross-lane argmax over the 32 cols held by l31=0..31 (same half).
    // Tie -> smaller index (jnp.argmax first-index semantics).
    #pragma unroll
    for (int m = 1; m < 32; m <<= 1) {
        #pragma unroll
        for (int e = 0; e < 16; ++e) {
            const float ov = __shfl_xor(best[e], m, 64);
            const int   oi = __shfl_xor(bidx[e], m, 64);
            if (ov > best[e] || (ov == best[e] && oi < bidx[e])) {
                best[e] = ov; bidx[e] = oi;
            }
        }
    }

    // Cross-chunk fold via packed-key atomicMax (r12/r15-proven): key =
    // mono(score)<<32 | (4095-col). Equal scores -> equal mono; larger
    // (4095-col) = smaller col wins = first-index. Deterministic.
    if (l31 == 0) {   // lanes 0 and 32 hold their half's rows
        #pragma unroll
        for (int e = 0; e < 16; ++e) {
            const int row = rowbase + (e & 3) + 8 * (e >> 2) + 4 * half;
            const unsigned u = __float_as_uint(best[e]);
            const unsigned mono = (u & 0x80000000u) ? ~u : (u | 0x80000000u);
            const unsigned long long key =
                ((unsigned long long)mono << 32) | (unsigned)(4095 - bidx[e]);
            atomicMax(&keys[row], key);
        }
    }
}

// ---------------------------------------------------------------------------
// Decode keys, gather LUT, write out (1024,8,10,2).
__global__ void reduce_lut_kernel(const unsigned long long* __restrict__ keys,
                                  const float* __restrict__ LUT,  // (10,4096,2)
                                  float* __restrict__ out) {
    const int row = blockIdx.x * blockDim.x + threadIdx.x;
    if (row >= M_ROWS) return;
    const unsigned long long key = keys[row];
    const int bi = 4095 - (int)(key & 0xFFFFFFFFull);
    const int pair = row / 10;
    const int c2   = row - pair * 10;
    const float* l = LUT + ((size_t)c2 * NCOLS + bi) * 2;
    out[row * 2 + 0] = l[0];
    out[row * 2 + 1] = l[1];
}

// ---------------------------------------------------------------------------
extern "C" void kernel_launch(void* const* d_in, const int* in_sizes, int n_in,
                              void* d_out, int out_size, void* d_ws, size_t ws_size,
                              hipStream_t stream) {
    const float* x   = (const float*)d_in[0];  // 1024*480
    const float* S   = (const float*)d_in[1];  // 30*2*15
    const float* T   = (const float*)d_in[2];  // 30*15
    const float* H   = (const float*)d_in[3];  // 45*4096
    const float* LUT = (const float*)d_in[4];  // 10*4096*2
    float* out = (float*)d_out;                // 1024*8*10*2

    _Float16* Bfrag = (_Float16*)d_ws;                        // 128*3072 halves
    unsigned long long* keys =
        (unsigned long long*)(Bfrag + (size_t)128 * GHALVES); // 81920 u64

    build_B_kernel<<<16, 256, 0, stream>>>(H, Bfrag, keys);
    // 2560 blocks x 8 waves (2 chunks x 4 row-tiles of 32 rows) = 128 rows
    // x 2 chunks per block; 5 EXACT fills at 2 blocks/CU residency.
    score_argmax_kernel<<<2560, 512, 0, stream>>>(x, S, T, Bfrag, keys);
    reduce_lut_kernel<<<M_ROWS / 256, 256, 0, stream>>>(keys, LUT, out);
}

// Round 17
// 180.422 us; speedup vs baseline: 1.3008x; 1.3008x over previous
//
#include <hip/hip_runtime.h>
#include <math.h>

// Problem constants (N = 1024)
#define M_ROWS  81920            // 1024*8*10 score rows
#define NCOLS   4096
#define KPAD    48               // 45 padded to 48 (3 k-tiles of 16 for 32x32x16)
#define NCHUNK  4
#define CHUNKC  (NCOLS / NCHUNK) // 1024 cols per chunk (one wave each)
#define CROUNDS (CHUNKC / 32)    // 32 col-rounds of 32 cols
#define GHALVES 3072             // _Float16 per 32-col group: 6 bufs * 512
#define LO_SCALE 4096.0f         // 2^12: keeps f16 residuals out of subnormal range
#define INV_LO   (1.0f / 4096.0f)

typedef _Float16 f16x8  __attribute__((ext_vector_type(8)));
typedef float    f32x16 __attribute__((ext_vector_type(16)));

// ws layout (0.75 MB):
//   Bfrag : _Float16[128 groups][6 bufs][512]   fragment-major
// Fragment-major: for 32-col group g, buffer f (f<3: hi k-tile f; f>=3: lo
// k-tile f-3), the 64 lanes' 16B MFMA B-fragments stored CONTIGUOUSLY at
// lane*16B -> one coalesced 1KB read per fragment.
//
// FINAL LADDER (r0-r16, score-kernel µs): THIS KERNEL (= r13) = 131 BEST.
// Wins: fragment-major layout (r4->r5: 195->137.8), ping-pong dbuf
// (r5->r13: 137.8->131). Falsified levers: occupancy via arg2 (r14:
// register-limited, 64 arch + 32 acc -> 4 waves/SIMD max); 64-row waves
// (r10/r11: +64 VGPR -> 2 waves/SIMD); LDS staging (r8/r9/r12: barrier
// lockstep or 1-block residency); 8-way stream sharing (r15: neutral);
// fill balancing via more waves (r16: per-wave fixed overhead ~4.6us/1000
// waves dominates -> regressed). Structural floor: L1 line traffic 2.0 GB
// (~51us), VALU ~41us, MFMA ~27us, no pipe >52% -- latency plateau with
// register-capped TLP. All structural escapes measured dead.
//
// Launch-bounds law (measured r0,r2,r3,r8,r14): arch-VGPR cap = 256/arg2;
// arg2 upper-bounds blocks/CU; actual residency register-limited.

// ---------------------------------------------------------------------------
// Build Bfrag: split H (45 x 4096, [d][n]) into hi/lo f16, emit in
// fragment-major order. Lane mapping within a buffer: lane = half*32 + c,
// holding col (g*32+c), k's [kt*16 + half*8, +8), pad k=45..47 zeroed.
__global__ void build_B_kernel(const float* __restrict__ H,
                               _Float16* __restrict__ Bfrag) {
    const int n = blockIdx.x * 256 + threadIdx.x;     // col [0,4096)
    _Float16 hi[KPAD], lo[KPAD];
    #pragma unroll
    for (int k = 0; k < 45; ++k) {
        const float h = H[k * NCOLS + n];
        const _Float16 h1 = (_Float16)h;
        hi[k] = h1;
        lo[k] = (_Float16)((h - (float)h1) * LO_SCALE);
    }
    #pragma unroll
    for (int k = 45; k < KPAD; ++k) { hi[k] = (_Float16)0.f; lo[k] = (_Float16)0.f; }

    const int g = n >> 5;
    const int c = n & 31;
    _Float16* gbase = Bfrag + (size_t)g * GHALVES;
    #pragma unroll
    for (int f = 0; f < 6; ++f) {
        const int kt = (f < 3) ? f : f - 3;
        const _Float16* src = ((f < 3) ? hi : lo) + kt * 16;
        #pragma unroll
        for (int h = 0; h < 2; ++h) {
            // lane = h*32 + c  ->  halves offset lane*8
            *(f16x8*)(gbase + f * 512 + (h * 32 + c) * 8) =
                *(const f16x8*)(src + h * 8);
        }
    }
}

// ---------------------------------------------------------------------------
// Fused MFMA GEMM + argmax + chunk-reduce + LUT gather.
// Block = 512 threads = 8 waves = 4 chunks x 2 row-tiles (32 rows each).
// wave w: chunk = w&3 (1024 cols), rtile = w>>2. Waves w and w+4 read the
// SAME B chunk (L1 reuse). Ping-pong double-buffered B prefetch hides the
// per-round L2 latency.
//
// 32x32 layouts: A[m=lane&31][k=(lane>>5)*8+j]; B[k=(lane>>5)*8+j][n=lane&31];
// C/D: col=lane&31, row=(reg&3)+8*(reg>>2)+4*(lane>>5)   (m74/m101-verified).
__global__ __launch_bounds__(512, 2) void score_argmax_kernel(
        const float* __restrict__ x,   // (1024, 480)
        const float* __restrict__ S,   // (30, 2, 15)
        const float* __restrict__ T,   // (30, 15)
        const _Float16* __restrict__ Bfrag,
        const float* __restrict__ LUT, // (10, 4096, 2)
        float* __restrict__ out) {     // (81920, 2)
    const int tid  = threadIdx.x;
    const int lane = tid & 63;
    const int l31  = lane & 31;
    const int half = lane >> 5;                       // 0 or 1
    const int wid   = tid >> 6;                       // wave id [0,8)
    const int chunk = wid & 3;                        // B-chunk [0,4)
    const int rtile = wid >> 2;                       // row-tile [0,2)
    const int rowblk = blockIdx.x * 64;               // block's first row
    const int rowbase = rowblk + rtile * 32;          // wave's first row

    __shared__ float lds_best[NCHUNK][64];
    __shared__ int   lds_bidx[NCHUNK][64];

    // ---- inline A: afr[kt][j] = y(rowbase + l31, kt*16 + half*8 + j)
    // y = sign(x4·S - T - 1e-4), exactly ±1/0 in f16; zero for k >= 45.
    f16x8 afr[3];
    {
        const int row  = rowbase + l31;
        const int pair = row / 10;
        const int c2   = row - pair * 10;
        const int a    = pair >> 3;
        const int b    = pair & 7;
        const float* xp = x + a * 480 + b * 60;
        #pragma unroll
        for (int kt = 0; kt < 3; ++kt) {
            #pragma unroll
            for (int j = 0; j < 8; ++j) {
                const int k    = kt * 16 + half * 8 + j;     // [0,48)
                const bool pad = (k >= 45);
                const int kcl  = pad ? 0 : k;                // clamp for safe addrs
                const int cc   = kcl / 15;                   // const-divisor magic
                const int kk   = kcl - cc * 15;
                const int c    = c2 * 3 + cc;
                const float x0 = xp[c * 2 + 0];
                const float x1 = xp[c * 2 + 1];
                float v = x0 * S[(c * 2 + 0) * 15 + kk] + x1 * S[(c * 2 + 1) * 15 + kk];
                v = v - T[c * 15 + kk] - 1e-4f;
                const float yv = (v > 0.f) ? 1.f : ((v < 0.f) ? -1.f : 0.f);
                afr[kt][j] = pad ? (_Float16)0.f : (_Float16)yv;
            }
        }
    }

    float best[16];
    int   bidx[16];
    #pragma unroll
    for (int e = 0; e < 16; ++e) { best[e] = -INFINITY; bidx[e] = 0; }

    const int colbase0 = chunk * CHUNKC;
    const int gbase0   = colbase0 >> 5;               // first group of chunk
    const _Float16* lanep = Bfrag + (size_t)lane * 8;

    // PREFETCH round rr (wrapped into [0,32) by caller): 6 x 1KB coalesced
#define PREFETCH(dst, rr) do {                                              \
        const _Float16* fp_ = lanep + (size_t)(gbase0 + (rr)) * GHALVES;    \
        _Pragma("unroll")                                                   \
        for (int f_ = 0; f_ < 6; ++f_)                                      \
            (dst)[f_] = *(const f16x8*)(fp_ + f_ * 512);                    \
    } while (0)

#define COMPUTE(buf, ct) do {                                               \
        f32x16 ch = {0.f};                                                  \
        f32x16 cl = {0.f};                                                  \
        ch = __builtin_amdgcn_mfma_f32_32x32x16_f16(afr[0], (buf)[0], ch, 0, 0, 0); \
        ch = __builtin_amdgcn_mfma_f32_32x32x16_f16(afr[1], (buf)[1], ch, 0, 0, 0); \
        ch = __builtin_amdgcn_mfma_f32_32x32x16_f16(afr[2], (buf)[2], ch, 0, 0, 0); \
        cl = __builtin_amdgcn_mfma_f32_32x32x16_f16(afr[0], (buf)[3], cl, 0, 0, 0); \
        cl = __builtin_amdgcn_mfma_f32_32x32x16_f16(afr[1], (buf)[4], cl, 0, 0, 0); \
        cl = __builtin_amdgcn_mfma_f32_32x32x16_f16(afr[2], (buf)[5], cl, 0, 0, 0); \
        const int mycol_ = colbase0 + (ct) * 32 + l31;                      \
        _Pragma("unroll")                                                   \
        for (int e_ = 0; e_ < 16; ++e_) {                                   \
            const float s_ = fmaf(cl[e_], INV_LO, ch[e_]);                  \
            if (s_ > best[e_]) bidx[e_] = mycol_;   /* cols ascend */       \
            best[e_] = fmaxf(best[e_], s_);                                 \
        }                                                                   \
    } while (0)

    // ping-pong x2 unroll: no per-round register copies; prefetch index
    // wraps &31 (stays inside the chunk: no overread, no ws slack needed).
    f16x8 cb[6], nb[6];
    PREFETCH(cb, 0);
    for (int it = 0; it < CROUNDS; it += 2) {
        PREFETCH(nb, it + 1);                 // it+1 <= 31: in range
        COMPUTE(cb, it);
        PREFETCH(cb, (it + 2) & 31);          // wrap: in range, values unused
        COMPUTE(nb, it + 1);
    }
#undef PREFETCH
#undef COMPUTE

    // Cross-lane argmax over the 32 cols held by l31=0..31 (same half).
    // Tie -> smaller index (jnp.argmax first-index semantics).
    #pragma unroll
    for (int m = 1; m < 32; m <<= 1) {
        #pragma unroll
        for (int e = 0; e < 16; ++e) {
            const float ov = __shfl_xor(best[e], m, 64);
            const int   oi = __shfl_xor(bidx[e], m, 64);
            if (ov > best[e] || (ov == best[e] && oi < bidx[e])) {
                best[e] = ov; bidx[e] = oi;
            }
        }
    }

    if (l31 == 0) {   // lanes 0 and 32 write their half's rows
        #pragma unroll
        for (int e = 0; e < 16; ++e) {
            const int r64 = rtile * 32 + (e & 3) + 8 * (e >> 2) + 4 * half;
            lds_best[chunk][r64] = best[e];
            lds_bidx[chunk][r64] = bidx[e];
        }
    }
    __syncthreads();

    // Fold the 4 chunk partials (ascending chunk + strict > == global
    // first-index argmax), gather LUT, write out (row-major (1024,8,10,2)).
    if (tid < 64) {
        const int row = rowblk + tid;
        float bv = lds_best[0][tid];
        int   bi = lds_bidx[0][tid];
        #pragma unroll
        for (int c = 1; c < NCHUNK; ++c) {
            const float v = lds_best[c][tid];
            const int   i = lds_bidx[c][tid];
            if (v > bv) { bv = v; bi = i; }
        }
        const int pair = row / 10;
        const int c2   = row - pair * 10;
        const float* l = LUT + ((size_t)c2 * NCOLS + bi) * 2;
        out[row * 2 + 0] = l[0];
        out[row * 2 + 1] = l[1];
    }
}

// ---------------------------------------------------------------------------
extern "C" void kernel_launch(void* const* d_in, const int* in_sizes, int n_in,
                              void* d_out, int out_size, void* d_ws, size_t ws_size,
                              hipStream_t stream) {
    const float* x   = (const float*)d_in[0];  // 1024*480
    const float* S   = (const float*)d_in[1];  // 30*2*15
    const float* T   = (const float*)d_in[2];  // 30*15
    const float* H   = (const float*)d_in[3];  // 45*4096
    const float* LUT = (const float*)d_in[4];  // 10*4096*2
    float* out = (float*)d_out;                // 1024*8*10*2

    _Float16* Bfrag = (_Float16*)d_ws;         // 128 groups * 3072 halves

    build_B_kernel<<<16, 256, 0, stream>>>(H, Bfrag);
    // 1280 blocks x 8 waves (4 chunks x 2 row-tiles of 32 rows) = 64 rows/blk.
    // (512,2): 16 waves/CU; 64 VGPR under the 128 cap.
    score_argmax_kernel<<<1280, 512, 0, stream>>>(x, S, T, Bfrag, LUT, out);
}